// Round 1
// baseline (304.994 us; speedup 1.0000x reference)
//
#include <hip/hip_runtime.h>

typedef unsigned short u16;
typedef unsigned short u16x8 __attribute__((ext_vector_type(8)));
typedef __bf16 bf16x8 __attribute__((ext_vector_type(8)));
typedef float f32x4 __attribute__((ext_vector_type(4)));

#define N_IMG 32
#define HW 3136       // 56*56
#define W56 56
#define NPIX (N_IMG * HW)   // 100352
#define KDIM 1152     // 9*128

__device__ __forceinline__ float bf2f(u16 u) {
    unsigned int x = ((unsigned int)u) << 16;
    return __builtin_bit_cast(float, x);
}
__device__ __forceinline__ u16 f2bf(float f) {
    unsigned int u = __builtin_bit_cast(unsigned int, f);
    unsigned int r = (u + 0x7FFFu + ((u >> 16) & 1u)) >> 16;
    return (u16)r;
}

// ---- prep: Bm[k][(r*3+s)*128+c] = sign(w[k][c][r][s]) as bf16 ----
__global__ void prep_w_kernel(const float* __restrict__ w, u16* __restrict__ Bm) {
    int i = blockIdx.x * 256 + threadIdx.x;
    if (i >= 128 * KDIM) return;
    int k  = i / KDIM;
    int kk = i - k * KDIM;
    int c  = kk & 127;
    int rs = kk >> 7;
    float v = w[(size_t)(k * 128 + c) * 9 + rs];
    float sv = (v > 0.f) ? 1.f : ((v < 0.f) ? -1.f : 0.f);
    Bm[i] = f2bf(sv);
}

// ---- NCHW f32 -> NHWC bf16 ----
__global__ void x_to_nhwc(const float* __restrict__ x, u16* __restrict__ xb) {
    __shared__ float tile[32][65];
    const int t = threadIdx.x;
    const int n = blockIdx.y;
    const int ct = blockIdx.x & 3;
    const int pt = blockIdx.x >> 2;   // 0..48
    const int c0 = ct * 32, p0 = pt * 64;
    {
        const int c  = t >> 3;        // 0..31
        const int pw = (t & 7) * 8;   // 0..56
        const size_t ib = ((size_t)(n * 128 + c0 + c)) * HW + p0 + pw;
        const float4 v0 = *(const float4*)(x + ib);
        const float4 v1 = *(const float4*)(x + ib + 4);
        tile[c][pw + 0] = v0.x; tile[c][pw + 1] = v0.y;
        tile[c][pw + 2] = v0.z; tile[c][pw + 3] = v0.w;
        tile[c][pw + 4] = v1.x; tile[c][pw + 5] = v1.y;
        tile[c][pw + 6] = v1.z; tile[c][pw + 7] = v1.w;
    }
    __syncthreads();
    {
        const int p  = t >> 2;        // 0..63
        const int cs = (t & 3) * 8;   // 0..24
        u16x8 o;
#pragma unroll
        for (int j = 0; j < 8; ++j) o[j] = f2bf(tile[cs + j][p]);
        *(u16x8*)(xb + ((size_t)(n * HW + p0 + p)) * 128 + c0 + cs) = o;
    }
}

// ---- conv as implicit GEMM, bf16 MFMA 16x16x32 ----
// A: act NHWC bf16 [NPIX][128]; B: Bm [128 kout][1152]; y: NHWC bf16 [NPIX][128]
__global__ __launch_bounds__(256) void conv_mfma(
    const u16* __restrict__ xb, const u16* __restrict__ Bm, u16* __restrict__ y)
{
    __shared__ __align__(16) u16 As[128 * 32];
    __shared__ __align__(16) u16 Bs[128 * 32];
    const int t = threadIdx.x;
    const int pm0 = blockIdx.x * 128;

    // staging
    const int prow  = t >> 1;          // 0..127
    const int chalf = (t & 1) * 16;    // u16 units
    const int sw    = (t >> 2) & 1;

    const int ps  = pm0 + prow;
    const int n   = ps / HW;
    const int rem = ps - n * HW;
    const int h   = rem / W56;
    const int w   = rem - h * W56;
    const u16* xrow = xb + (size_t)ps * 128 + chalf;
    const u16* brow = Bm + (size_t)prow * KDIM + chalf;

    u16* aw0 = &As[prow * 32 + chalf + sw * 8];
    u16* aw1 = &As[prow * 32 + chalf + (1 - sw) * 8];
    u16* bw0 = &Bs[prow * 32 + chalf + sw * 8];
    u16* bw1 = &Bs[prow * 32 + chalf + (1 - sw) * 8];

    // mfma
    const int lane = t & 63;
    const int wid  = t >> 6;
    const int m0   = (wid >> 1) * 64;
    const int n0   = (wid & 1) * 64;
    const int lrow = lane & 15;
    const int lkof = (lane >> 4) * 8;

    f32x4 acc[4][4] = {};

#pragma unroll 1
    for (int rs = 0; rs < 9; ++rs) {
        const int r = rs / 3;
        const int s = rs - r * 3;
        const int dh = h + r - 1, dw = w + s - 1;
        const bool valid = ((unsigned)dh < 56u) && ((unsigned)dw < 56u);
        const u16* asrc = xrow + ((r - 1) * W56 + (s - 1)) * 128;
        const u16* bsrc = brow + rs * 128;
#pragma unroll 1
        for (int c0 = 0; c0 < 128; c0 += 32) {
            u16x8 av0 = (u16x8)0, av1 = (u16x8)0;
            if (valid) {
                av0 = *(const u16x8*)(asrc + c0);
                av1 = *(const u16x8*)(asrc + c0 + 8);
            }
            u16x8 bv0 = *(const u16x8*)(bsrc + c0);
            u16x8 bv1 = *(const u16x8*)(bsrc + c0 + 8);
            *(u16x8*)aw0 = sw ? av1 : av0;
            *(u16x8*)aw1 = sw ? av0 : av1;
            *(u16x8*)bw0 = sw ? bv1 : bv0;
            *(u16x8*)bw1 = sw ? bv0 : bv1;
            __syncthreads();
            bf16x8 af[4], bfr[4];
#pragma unroll
            for (int mi = 0; mi < 4; ++mi)
                af[mi] = *(const bf16x8*)&As[(m0 + mi * 16 + lrow) * 32 + lkof];
#pragma unroll
            for (int ni = 0; ni < 4; ++ni)
                bfr[ni] = *(const bf16x8*)&Bs[(n0 + ni * 16 + lrow) * 32 + lkof];
#pragma unroll
            for (int mi = 0; mi < 4; ++mi)
#pragma unroll
                for (int ni = 0; ni < 4; ++ni)
                    acc[mi][ni] = __builtin_amdgcn_mfma_f32_16x16x32_bf16(
                        af[mi], bfr[ni], acc[mi][ni], 0, 0, 0);
            __syncthreads();
        }
    }

    const int orow = (lane >> 4) * 4;
    const int ocol = lane & 15;
#pragma unroll
    for (int mi = 0; mi < 4; ++mi)
#pragma unroll
        for (int ni = 0; ni < 4; ++ni)
#pragma unroll
            for (int q = 0; q < 4; ++q) {
                int m  = m0 + mi * 16 + orow + q;
                int nn = n0 + ni * 16 + ocol;
                y[(size_t)(pm0 + m) * 128 + nn] = f2bf(acc[mi][ni][q]);
            }
}

// ---- BN stats stage 1: per-(block,channel) partial sums over rows ----
__global__ void stats_kernel(const u16* __restrict__ y, float2* __restrict__ partial) {
    __shared__ float sb[256], sb2[256];
    const int t = threadIdx.x;
    const int c = t & 127;
    const int half = t >> 7;
    const int r0 = blockIdx.x * 392;    // 100352/256
    float s = 0.f, s2 = 0.f;
    for (int i = half; i < 392; i += 2) {
        float v = bf2f(y[(size_t)(r0 + i) * 128 + c]);
        s += v; s2 += v * v;
    }
    sb[t] = s; sb2[t] = s2;
    __syncthreads();
    if (t < 128)
        partial[(size_t)blockIdx.x * 128 + t] =
            make_float2(sb[t] + sb[t + 128], sb2[t] + sb2[t + 128]);
}

// ---- BN stats stage 2: coef[c] = (a, b) with y' = a*y + b ----
__global__ void stats_finalize(const float2* __restrict__ partial,
                               const float* __restrict__ gamma, const float* __restrict__ beta,
                               float2* __restrict__ coef) {
    const int c = threadIdx.x;   // 128
    double s = 0.0, s2 = 0.0;
    for (int b = 0; b < 256; ++b) {
        float2 p = partial[b * 128 + c];
        s += (double)p.x; s2 += (double)p.y;
    }
    const double inv_n = 1.0 / (double)NPIX;
    double mean = s * inv_n;
    double var  = s2 * inv_n - mean * mean;
    if (var < 0.0) var = 0.0;
    float inv = rsqrtf((float)var + 1e-5f);
    float a = gamma[c] * inv;
    coef[c] = make_float2(a, beta[c] - (float)mean * a);
}

// ---- BN1 + ReLU -> bf16 NHWC ----
__global__ void bnrelu_kernel(const u16* __restrict__ y, const float2* __restrict__ coef,
                              u16* __restrict__ out) {
    __shared__ float2 sc[128];
    const int t = threadIdx.x;
    if (t < 128) sc[t] = coef[t];
    __syncthreads();
    size_t i = (size_t)blockIdx.x * 256 + t;
    u16x8 v = *(const u16x8*)(y + i * 8);
    int cb = (int)((i & 15) * 8);
    u16x8 o;
#pragma unroll
    for (int j = 0; j < 8; ++j) {
        float2 k = sc[cb + j];
        float f = bf2f(v[j]) * k.x + k.y;
        o[j] = f2bf(fmaxf(f, 0.f));
    }
    *(u16x8*)(out + i * 8) = o;
}

// ---- BN2 + residual + ReLU + NHWC->NCHW f32 ----
__global__ void bn_add_relu_nchw(const u16* __restrict__ y2, const float2* __restrict__ coef,
                                 const float* __restrict__ x, float* __restrict__ out) {
    __shared__ float tile[32][65];
    __shared__ float2 sc[32];
    const int t = threadIdx.x;
    const int n = blockIdx.y;
    const int ct = blockIdx.x & 3;
    const int pt = blockIdx.x >> 2;
    const int c0 = ct * 32, p0 = pt * 64;
    if (t < 32) sc[t] = coef[c0 + t];
    __syncthreads();
    {
        const int p  = t >> 2;
        const int cs = (t & 3) * 8;
        const u16x8 v = *(const u16x8*)(y2 + ((size_t)(n * HW + p0 + p)) * 128 + c0 + cs);
#pragma unroll
        for (int j = 0; j < 8; ++j) {
            float2 k = sc[cs + j];
            tile[cs + j][p] = bf2f(v[j]) * k.x + k.y;
        }
    }
    __syncthreads();
    {
        const int c  = t >> 3;
        const int pw = (t & 7) * 8;
        const size_t ob = ((size_t)(n * 128 + c0 + c)) * HW + p0 + pw;
        const float4 x0 = *(const float4*)(x + ob);
        const float4 x1 = *(const float4*)(x + ob + 4);
        float4 o0, o1;
        o0.x = fmaxf(tile[c][pw + 0] + x0.x, 0.f);
        o0.y = fmaxf(tile[c][pw + 1] + x0.y, 0.f);
        o0.z = fmaxf(tile[c][pw + 2] + x0.z, 0.f);
        o0.w = fmaxf(tile[c][pw + 3] + x0.w, 0.f);
        o1.x = fmaxf(tile[c][pw + 4] + x1.x, 0.f);
        o1.y = fmaxf(tile[c][pw + 5] + x1.y, 0.f);
        o1.z = fmaxf(tile[c][pw + 6] + x1.z, 0.f);
        o1.w = fmaxf(tile[c][pw + 7] + x1.w, 0.f);
        *(float4*)(out + ob) = o0;
        *(float4*)(out + ob + 4) = o1;
    }
}

extern "C" void kernel_launch(void* const* d_in, const int* in_sizes, int n_in,
                              void* d_out, int out_size, void* d_ws, size_t ws_size,
                              hipStream_t stream) {
    const float* x  = (const float*)d_in[0];
    const float* w1 = (const float*)d_in[1];
    const float* g1 = (const float*)d_in[2];
    const float* b1 = (const float*)d_in[3];
    const float* w2 = (const float*)d_in[4];
    const float* g2 = (const float*)d_in[5];
    const float* b2 = (const float*)d_in[6];
    float* out = (float*)d_out;
    char* ws = (char*)d_ws;

    const size_t BIG = (size_t)NPIX * 128 * 2;   // 25690112 bytes
    u16*    xb   = (u16*)(ws);                    // NHWC bf16 x; reused as out1
    u16*    ybuf = (u16*)(ws + BIG);              // conv output NHWC bf16
    u16*    Bm1  = (u16*)(ws + 2 * BIG);
    u16*    Bm2  = (u16*)(ws + 2 * BIG + 294912);
    float2* part = (float2*)(ws + 2 * BIG + 2 * 294912);
    float2* cf1  = (float2*)(ws + 2 * BIG + 2 * 294912 + 262144);
    float2* cf2  = (float2*)(ws + 2 * BIG + 2 * 294912 + 262144 + 1024);

    prep_w_kernel<<<576, 256, 0, stream>>>(w1, Bm1);
    prep_w_kernel<<<576, 256, 0, stream>>>(w2, Bm2);
    x_to_nhwc<<<dim3(196, 32), 256, 0, stream>>>(x, xb);

    conv_mfma<<<NPIX / 128, 256, 0, stream>>>(xb, Bm1, ybuf);
    stats_kernel<<<256, 256, 0, stream>>>(ybuf, part);
    stats_finalize<<<1, 128, 0, stream>>>(part, g1, b1, cf1);
    bnrelu_kernel<<<NPIX * 128 / (256 * 8), 256, 0, stream>>>(ybuf, cf1, xb);  // xb := out1

    conv_mfma<<<NPIX / 128, 256, 0, stream>>>(xb, Bm2, ybuf);
    stats_kernel<<<256, 256, 0, stream>>>(ybuf, part);
    stats_finalize<<<1, 128, 0, stream>>>(part, g2, b2, cf2);
    bn_add_relu_nchw<<<dim3(196, 32), 256, 0, stream>>>(ybuf, cf2, x, out);
}

// Round 2
// 158.516 us; speedup vs baseline: 1.9241x; 1.9241x over previous
//
#include <hip/hip_runtime.h>

typedef unsigned short u16;
typedef unsigned short u16x8 __attribute__((ext_vector_type(8)));
typedef __bf16 bf16x8 __attribute__((ext_vector_type(8)));
typedef float f32x4 __attribute__((ext_vector_type(4)));

#define HW 3136        // 56*56
#define NPIX 100352    // 32*3136
#define PADR 3364      // 58*58 padded rows per image
#define KD 1152        // 9*128

__device__ __forceinline__ float bf2f(u16 u) {
    unsigned int x = ((unsigned int)u) << 16;
    return __builtin_bit_cast(float, x);
}
__device__ __forceinline__ u16 f2bf(float f) {
    unsigned int u = __builtin_bit_cast(unsigned int, f);
    return (u16)((u + 0x7FFFu + ((u >> 16) & 1u)) >> 16);
}
__device__ __forceinline__ void gload16(const void* g, void* l) {
    __builtin_amdgcn_global_load_lds(
        (const __attribute__((address_space(1))) unsigned int*)g,
        (__attribute__((address_space(3))) unsigned int*)l, 16, 0, 0);
}

// ---- setup: binarize both weight sets + zero padded-buffer borders ----
// Bm[k][(r*3+s)*128+c] = sign(w[k][c][r][s]) as bf16
__global__ void setup_kernel(const float* __restrict__ w1, const float* __restrict__ w2,
                             u16* __restrict__ Bm1, u16* __restrict__ Bm2,
                             u16* __restrict__ xbp) {
    const int b = blockIdx.x;
    const int t = threadIdx.x;
    if (b < 1152) {
        const float* w = (b < 576) ? w1 : w2;
        u16* Bm = (b < 576) ? Bm1 : Bm2;
        int i = (b % 576) * 256 + t;       // < 147456 exactly
        int k  = i / KD;
        int kk = i - k * KD;
        int c  = kk & 127;
        int rs = kk >> 7;
        float v = w[(size_t)(k * 128 + c) * 9 + rs];
        float sv = (v > 0.f) ? 1.f : ((v < 0.f) ? -1.f : 0.f);
        Bm[i] = f2bf(sv);
    } else {
        // zero borders: 228 border pixels per image * 32 images * 16 chunks
        int idx = (b - 1152) * 256 + t;    // < 116736 exactly
        int pix = idx >> 4;
        int cc  = idx & 15;
        int n  = pix / 228;
        int pb = pix - n * 228;
        int h, w;
        if (pb < 58)       { h = 0;  w = pb; }
        else if (pb < 116) { h = 57; w = pb - 58; }
        else { int q = pb - 116; h = 1 + (q >> 1); w = (q & 1) ? 57 : 0; }
        u16x8 z = {};
        *(u16x8*)(xbp + ((size_t)(n * PADR + h * 58 + w)) * 128 + cc * 8) = z;
    }
}

// ---- NCHW f32 -> padded NHWC bf16 (interior only) ----
__global__ void x_to_nhwc(const float* __restrict__ x, u16* __restrict__ xbp) {
    __shared__ float tile[32][65];
    const int t = threadIdx.x;
    const int n = blockIdx.y;
    const int ct = blockIdx.x & 3;
    const int pt = blockIdx.x >> 2;   // 0..48
    const int c0 = ct * 32, p0 = pt * 64;
    {
        const int c  = t >> 3;
        const int pw = (t & 7) * 8;
        const size_t ib = ((size_t)(n * 128 + c0 + c)) * HW + p0 + pw;
        const float4 v0 = *(const float4*)(x + ib);
        const float4 v1 = *(const float4*)(x + ib + 4);
        tile[c][pw + 0] = v0.x; tile[c][pw + 1] = v0.y;
        tile[c][pw + 2] = v0.z; tile[c][pw + 3] = v0.w;
        tile[c][pw + 4] = v1.x; tile[c][pw + 5] = v1.y;
        tile[c][pw + 6] = v1.z; tile[c][pw + 7] = v1.w;
    }
    __syncthreads();
    {
        const int pl = t >> 2;
        const int cs = (t & 3) * 8;
        const int p  = p0 + pl;
        const int h  = p / 56;
        const int w  = p - h * 56;
        u16x8 o;
#pragma unroll
        for (int j = 0; j < 8; ++j) o[j] = f2bf(tile[cs + j][pl]);
        *(u16x8*)(xbp + ((size_t)(n * PADR + (h + 1) * 58 + (w + 1))) * 128 + c0 + cs) = o;
    }
}

// ---- conv as implicit GEMM + fused per-block BN stats ----
// xbp: padded NHWC bf16; Bm: [128][1152] sign weights; y: [NPIX][128] bf16
// partial: [128 c][784 blk] float2(sum, sumsq)
__global__ __launch_bounds__(256, 2) void conv_mfma(
    const u16* __restrict__ xbp, const u16* __restrict__ Bm,
    u16* __restrict__ y, float2* __restrict__ partial)
{
    __shared__ __align__(16) u16 smem[32768];   // 64 KB: As | Bs, reused by epilogue
    u16* As = smem;
    u16* Bs = smem + 16384;
    const int t = threadIdx.x;
    const int bid = blockIdx.x;
    const int pm0 = bid * 128;
    const int wid  = t >> 6;
    const int lane = t & 63;
    const int lrow = lane & 15;
    const int lhk  = lane >> 4;
    const int m0 = (wid >> 1) * 64;
    const int n0 = (wid & 1) * 64;

    // --- staging source offsets (u16 units), chunk-swizzled: chunk' = chunk ^ (row&7)
    const int sub = t >> 4;          // 0..15 (row-within-16 group)
    const int chunkS = (t & 15) ^ (sub & 7);
    int aoff[8], boff[8];
#pragma unroll
    for (int j = 0; j < 8; ++j) {
        int row = j * 16 + sub;      // LDS tile row 0..127
        int ps  = pm0 + row;         // output pixel
        int n   = ps / HW;
        int rem = ps - n * HW;
        int h   = rem / 56;
        int w   = rem - h * 56;
        aoff[j] = (n * PADR + (h + 1) * 58 + (w + 1)) * 128 + chunkS * 8;
        boff[j] = row * KD + chunkS * 8;
    }
    u16* dA = As + wid * 512;        // + j*2048 ; HW adds lane*16B
    u16* dB = Bs + wid * 512;

    f32x4 acc[4][4] = {};

#pragma unroll 1
    for (int rs = 0; rs < 9; ++rs) {
        const int r = rs / 3, s = rs - r * 3;
        const int ashift = ((r - 1) * 58 + (s - 1)) * 128;   // signed u16 offset
        const int bshift = rs * 128;
#pragma unroll
        for (int j = 0; j < 8; ++j) {
            gload16(xbp + aoff[j] + ashift, dA + j * 2048);
            gload16(Bm  + boff[j] + bshift, dB + j * 2048);
        }
        __syncthreads();
#pragma unroll
        for (int kc = 0; kc < 4; ++kc) {
            const int ck = (((kc << 2) | lhk) ^ (lrow & 7)) << 3;   // swizzled 16B-chunk
            bf16x8 af[4], bv[4];
#pragma unroll
            for (int mi = 0; mi < 4; ++mi)
                af[mi] = *(const bf16x8*)&As[(m0 + mi * 16 + lrow) * 128 + ck];
#pragma unroll
            for (int ni = 0; ni < 4; ++ni)
                bv[ni] = *(const bf16x8*)&Bs[(n0 + ni * 16 + lrow) * 128 + ck];
#pragma unroll
            for (int mi = 0; mi < 4; ++mi)
#pragma unroll
                for (int ni = 0; ni < 4; ++ni)
                    acc[mi][ni] = __builtin_amdgcn_mfma_f32_16x16x32_bf16(
                        af[mi], bv[ni], acc[mi][ni], 0, 0, 0);
        }
        __syncthreads();
    }

    // --- fused per-block BN stats (per channel over this block's 128 pixels)
    float sv[4], qv[4];
#pragma unroll
    for (int ni = 0; ni < 4; ++ni) {
        float a = 0.f, b = 0.f;
#pragma unroll
        for (int mi = 0; mi < 4; ++mi)
#pragma unroll
            for (int q = 0; q < 4; ++q) { float v = acc[mi][ni][q]; a += v; b += v * v; }
        a += __shfl_xor(a, 16); a += __shfl_xor(a, 32);
        b += __shfl_xor(b, 16); b += __shfl_xor(b, 32);
        sv[ni] = a; qv[ni] = b;
    }
    float2* sred = (float2*)(smem + 20480);   // byte 40960, past transpose tile
    if (lane < 16) {
#pragma unroll
        for (int ni = 0; ni < 4; ++ni)
            sred[wid * 64 + ni * 16 + lane] = make_float2(sv[ni], qv[ni]);
    }

    // --- transpose acc -> LDS tile [128 px][136 pad] bf16, then coalesced store
#pragma unroll
    for (int mi = 0; mi < 4; ++mi)
#pragma unroll
        for (int ni = 0; ni < 4; ++ni)
#pragma unroll
            for (int q = 0; q < 4; ++q)
                smem[(m0 + mi * 16 + lhk * 4 + q) * 136 + n0 + ni * 16 + lrow] =
                    f2bf(acc[mi][ni][q]);
    __syncthreads();
    {
        const int px = t >> 1, half = t & 1;
        const u16* src = &smem[px * 136 + half * 64];
        u16* dst = y + (size_t)(pm0 + px) * 128 + half * 64;
#pragma unroll
        for (int j = 0; j < 8; ++j)
            *(u16x8*)(dst + j * 8) = *(const u16x8*)(src + j * 8);
    }
    if (t < 128) {
        const int ni = (t >> 4) & 3, oc = t & 15, hi = t >> 6;
        float2 u = sred[hi * 64 + ni * 16 + oc];
        float2 v = sred[(hi + 2) * 64 + ni * 16 + oc];
        partial[(size_t)t * 784 + bid] = make_float2(u.x + v.x, u.y + v.y);
    }
}

// ---- reduce partials -> BN coef (a,b): y' = a*y + b ----
__global__ void stats_finalize(const float2* __restrict__ partial,
                               const float* __restrict__ gamma, const float* __restrict__ beta,
                               float2* __restrict__ coef) {
    __shared__ float ss[256], ss2[256];
    const int c = blockIdx.x, t = threadIdx.x;
    const float2* pc = partial + (size_t)c * 784;
    float s = 0.f, s2 = 0.f;
    for (int i = t; i < 784; i += 256) { float2 v = pc[i]; s += v.x; s2 += v.y; }
    ss[t] = s; ss2[t] = s2;
    __syncthreads();
    for (int o = 128; o > 0; o >>= 1) {
        if (t < o) { ss[t] += ss[t + o]; ss2[t] += ss2[t + o]; }
        __syncthreads();
    }
    if (t == 0) {
        double mean = (double)ss[0] / (double)NPIX;
        double var  = (double)ss2[0] / (double)NPIX - mean * mean;
        if (var < 0.0) var = 0.0;
        float inv = rsqrtf((float)var + 1e-5f);
        float a = gamma[c] * inv;
        coef[c] = make_float2(a, beta[c] - (float)mean * a);
    }
}

// ---- BN1 + ReLU: y (linear NHWC) -> padded NHWC bf16 (interior) ----
__global__ void bnrelu_kernel(const u16* __restrict__ y, const float2* __restrict__ coef,
                              u16* __restrict__ xbp) {
    __shared__ float2 sc[128];
    const int t = threadIdx.x;
    if (t < 128) sc[t] = coef[t];
    __syncthreads();
    size_t i = (size_t)blockIdx.x * 256 + t;
    u16x8 v = *(const u16x8*)(y + i * 8);
    int p  = (int)(i >> 4);
    int c0 = (int)(i & 15) * 8;
    int n   = p / HW;
    int rem = p - n * HW;
    int h   = rem / 56;
    int w   = rem - h * 56;
    u16x8 o;
#pragma unroll
    for (int j = 0; j < 8; ++j) {
        float2 k = sc[c0 + j];
        o[j] = f2bf(fmaxf(bf2f(v[j]) * k.x + k.y, 0.f));
    }
    *(u16x8*)(xbp + ((size_t)(n * PADR + (h + 1) * 58 + (w + 1))) * 128 + c0) = o;
}

// ---- BN2 + residual + ReLU + NHWC->NCHW f32 ----
__global__ void bn_add_relu_nchw(const u16* __restrict__ y2, const float2* __restrict__ coef,
                                 const float* __restrict__ x, float* __restrict__ out) {
    __shared__ float tile[32][65];
    __shared__ float2 sc[32];
    const int t = threadIdx.x;
    const int n = blockIdx.y;
    const int ct = blockIdx.x & 3;
    const int pt = blockIdx.x >> 2;
    const int c0 = ct * 32, p0 = pt * 64;
    if (t < 32) sc[t] = coef[c0 + t];
    __syncthreads();
    {
        const int p  = t >> 2;
        const int cs = (t & 3) * 8;
        const u16x8 v = *(const u16x8*)(y2 + ((size_t)(n * HW + p0 + p)) * 128 + c0 + cs);
#pragma unroll
        for (int j = 0; j < 8; ++j) {
            float2 k = sc[cs + j];
            tile[cs + j][p] = bf2f(v[j]) * k.x + k.y;
        }
    }
    __syncthreads();
    {
        const int c  = t >> 3;
        const int pw = (t & 7) * 8;
        const size_t ob = ((size_t)(n * 128 + c0 + c)) * HW + p0 + pw;
        const float4 x0 = *(const float4*)(x + ob);
        const float4 x1 = *(const float4*)(x + ob + 4);
        float4 o0, o1;
        o0.x = fmaxf(tile[c][pw + 0] + x0.x, 0.f);
        o0.y = fmaxf(tile[c][pw + 1] + x0.y, 0.f);
        o0.z = fmaxf(tile[c][pw + 2] + x0.z, 0.f);
        o0.w = fmaxf(tile[c][pw + 3] + x0.w, 0.f);
        o1.x = fmaxf(tile[c][pw + 4] + x1.x, 0.f);
        o1.y = fmaxf(tile[c][pw + 5] + x1.y, 0.f);
        o1.z = fmaxf(tile[c][pw + 6] + x1.z, 0.f);
        o1.w = fmaxf(tile[c][pw + 7] + x1.w, 0.f);
        *(float4*)(out + ob) = o0;
        *(float4*)(out + ob + 4) = o1;
    }
}

extern "C" void kernel_launch(void* const* d_in, const int* in_sizes, int n_in,
                              void* d_out, int out_size, void* d_ws, size_t ws_size,
                              hipStream_t stream) {
    const float* x  = (const float*)d_in[0];
    const float* w1 = (const float*)d_in[1];
    const float* g1 = (const float*)d_in[2];
    const float* b1 = (const float*)d_in[3];
    const float* w2 = (const float*)d_in[4];
    const float* g2 = (const float*)d_in[5];
    const float* b2 = (const float*)d_in[6];
    float* out = (float*)d_out;
    char* ws = (char*)d_ws;

    u16*    xbp  = (u16*)(ws);                         // padded NHWC, 27557888 B (reused as out1)
    u16*    ybuf = (u16*)(ws + 27557888);              // conv out NHWC, 25690112 B
    u16*    Bm1  = (u16*)(ws + 53248000);              // 294912 B
    u16*    Bm2  = (u16*)(ws + 53542912);              // 294912 B
    float2* part = (float2*)(ws + 53837824);           // 802816 B
    float2* cf1  = (float2*)(ws + 54640640);
    float2* cf2  = (float2*)(ws + 54641664);

    setup_kernel<<<1608, 256, 0, stream>>>(w1, w2, Bm1, Bm2, xbp);
    x_to_nhwc<<<dim3(196, 32), 256, 0, stream>>>(x, xbp);

    conv_mfma<<<784, 256, 0, stream>>>(xbp, Bm1, ybuf, part);
    stats_finalize<<<128, 256, 0, stream>>>(part, g1, b1, cf1);
    bnrelu_kernel<<<6272, 256, 0, stream>>>(ybuf, cf1, xbp);   // xbp interior := out1

    conv_mfma<<<784, 256, 0, stream>>>(xbp, Bm2, ybuf, part);
    stats_finalize<<<128, 256, 0, stream>>>(part, g2, b2, cf2);
    bn_add_relu_nchw<<<dim3(196, 32), 256, 0, stream>>>(ybuf, cf2, x, out);
}

// Round 3
// 148.508 us; speedup vs baseline: 2.0537x; 1.0674x over previous
//
#include <hip/hip_runtime.h>

typedef unsigned short u16;
typedef unsigned short u16x8 __attribute__((ext_vector_type(8)));
typedef __bf16 bf16x8 __attribute__((ext_vector_type(8)));
typedef float f32x4 __attribute__((ext_vector_type(4)));

#define HW 3136        // 56*56
#define NPIX 100352    // 32*3136
#define PADR 3364      // 58*58 padded rows per image
#define KD 1152        // 9*128

__device__ __forceinline__ float bf2f(u16 u) {
    unsigned int x = ((unsigned int)u) << 16;
    return __builtin_bit_cast(float, x);
}
__device__ __forceinline__ u16 f2bf(float f) {
    unsigned int u = __builtin_bit_cast(unsigned int, f);
    return (u16)((u + 0x7FFFu + ((u >> 16) & 1u)) >> 16);
}
__device__ __forceinline__ void gload16(const void* g, void* l) {
    __builtin_amdgcn_global_load_lds(
        (const __attribute__((address_space(1))) unsigned int*)g,
        (__attribute__((address_space(3))) unsigned int*)l, 16, 0, 0);
}

// ---- setup: binarize both weight sets + zero padded-buffer borders ----
__global__ void setup_kernel(const float* __restrict__ w1, const float* __restrict__ w2,
                             u16* __restrict__ Bm1, u16* __restrict__ Bm2,
                             u16* __restrict__ xbp) {
    const int b = blockIdx.x;
    const int t = threadIdx.x;
    if (b < 1152) {
        const float* w = (b < 576) ? w1 : w2;
        u16* Bm = (b < 576) ? Bm1 : Bm2;
        int i = (b % 576) * 256 + t;
        int k  = i / KD;
        int kk = i - k * KD;
        int c  = kk & 127;
        int rs = kk >> 7;
        float v = w[(size_t)(k * 128 + c) * 9 + rs];
        float sv = (v > 0.f) ? 1.f : ((v < 0.f) ? -1.f : 0.f);
        Bm[i] = f2bf(sv);
    } else {
        int idx = (b - 1152) * 256 + t;
        int pix = idx >> 4;
        int cc  = idx & 15;
        int n  = pix / 228;
        int pb = pix - n * 228;
        int h, w;
        if (pb < 58)       { h = 0;  w = pb; }
        else if (pb < 116) { h = 57; w = pb - 58; }
        else { int q = pb - 116; h = 1 + (q >> 1); w = (q & 1) ? 57 : 0; }
        u16x8 z = {};
        *(u16x8*)(xbp + ((size_t)(n * PADR + h * 58 + w)) * 128 + cc * 8) = z;
    }
}

// ---- NCHW f32 -> padded NHWC bf16 (interior only) ----
__global__ void x_to_nhwc(const float* __restrict__ x, u16* __restrict__ xbp) {
    __shared__ float tile[32][65];
    const int t = threadIdx.x;
    const int n = blockIdx.y;
    const int ct = blockIdx.x & 3;
    const int pt = blockIdx.x >> 2;
    const int c0 = ct * 32, p0 = pt * 64;
    {
        const int c  = t >> 3;
        const int pw = (t & 7) * 8;
        const size_t ib = ((size_t)(n * 128 + c0 + c)) * HW + p0 + pw;
        const float4 v0 = *(const float4*)(x + ib);
        const float4 v1 = *(const float4*)(x + ib + 4);
        tile[c][pw + 0] = v0.x; tile[c][pw + 1] = v0.y;
        tile[c][pw + 2] = v0.z; tile[c][pw + 3] = v0.w;
        tile[c][pw + 4] = v1.x; tile[c][pw + 5] = v1.y;
        tile[c][pw + 6] = v1.z; tile[c][pw + 7] = v1.w;
    }
    __syncthreads();
    {
        const int pl = t >> 2;
        const int cs = (t & 3) * 8;
        const int p  = p0 + pl;
        const int h  = p / 56;
        const int w  = p - h * 56;
        u16x8 o;
#pragma unroll
        for (int j = 0; j < 8; ++j) o[j] = f2bf(tile[cs + j][pl]);
        *(u16x8*)(xbp + ((size_t)(n * PADR + (h + 1) * 58 + (w + 1))) * 128 + c0 + cs) = o;
    }
}

// ---- conv implicit GEMM, 2-phase double-buffered (T3), fused BN stats ----
// Phases p=0..17: rs=p>>1, kh=p&1. Buffers (u16 offsets into smem):
//   A0=0, B0=8192, A1=16384, B1=24576 ; each tile [128 rows][64 ch] = 16 KB
#define A0 0
#define B0 8192
#define A1 16384
#define B1 24576

__global__ __launch_bounds__(256, 2) void conv_mfma(
    const u16* __restrict__ xbp, const u16* __restrict__ Bm,
    u16* __restrict__ y, float2* __restrict__ partial)
{
    __shared__ __align__(16) u16 smem[32768];   // 64 KB
    const int t = threadIdx.x;
    const int bid = blockIdx.x;
    const int pm0 = bid * 128;
    const int wid  = t >> 6;
    const int lane = t & 63;
    const int lrow = lane & 15;
    const int lhk  = lane >> 4;
    const int m0 = (wid >> 1) * 64;
    const int n0 = (wid & 1) * 64;

    // staging: instr j=0..3 covers 8-row group g=wid*4+j; lane -> row g*8+(lane>>3),
    // dest chunk lane&7 (linear), source chunk (lane&7)^(lane>>3) (inverse swizzle)
    const int rsub = lane >> 3;
    const int csrc = (lane & 7) ^ rsub;
    int apix[4], bbase[4];
#pragma unroll
    for (int j = 0; j < 4; ++j) {
        int row = (wid * 4 + j) * 8 + rsub;
        int ps  = pm0 + row;
        int n   = ps / HW;
        int rem = ps - n * HW;
        int h   = rem / 56;
        int w   = rem - h * 56;
        apix[j]  = (n * PADR + (h + 1) * 58 + (w + 1)) * 128 + csrc * 8;
        bbase[j] = row * KD + csrc * 8;
    }

    f32x4 acc[4][4] = {};

#define STAGE(AOFF, BOFF, p) do {                                              \
    int rs_ = (p) >> 1; int r_ = rs_ / 3; int s_ = rs_ - r_ * 3;               \
    int ash = ((r_ - 1) * 58 + (s_ - 1)) * 128 + ((p) & 1) * 64;               \
    int bsh = (p) * 64;                                                        \
    _Pragma("unroll")                                                          \
    for (int j = 0; j < 4; ++j) {                                              \
        gload16(xbp + apix[j] + ash, smem + (AOFF) + (wid * 4 + j) * 512);     \
        gload16(Bm + bbase[j] + bsh, smem + (BOFF) + (wid * 4 + j) * 512);     \
    } } while (0)

#define COMPUTE(AOFF, BOFF) do {                                               \
    _Pragma("unroll")                                                          \
    for (int kc = 0; kc < 2; ++kc) {                                           \
        bf16x8 af[4], bv[4];                                                   \
        _Pragma("unroll")                                                      \
        for (int mi = 0; mi < 4; ++mi) {                                       \
            int ck = (((kc << 2) | lhk) ^ (lrow & 7)) << 3;                    \
            af[mi] = *(const bf16x8*)&smem[(AOFF) + (m0 + mi * 16 + lrow) * 64 + ck]; \
        }                                                                      \
        _Pragma("unroll")                                                      \
        for (int ni = 0; ni < 4; ++ni) {                                       \
            int ck = (((kc << 2) | lhk) ^ (lrow & 7)) << 3;                    \
            bv[ni] = *(const bf16x8*)&smem[(BOFF) + (n0 + ni * 16 + lrow) * 64 + ck]; \
        }                                                                      \
        __builtin_amdgcn_s_setprio(1);                                         \
        _Pragma("unroll")                                                      \
        for (int mi = 0; mi < 4; ++mi)                                         \
        _Pragma("unroll")                                                      \
            for (int ni = 0; ni < 4; ++ni)                                     \
                acc[mi][ni] = __builtin_amdgcn_mfma_f32_16x16x32_bf16(         \
                    af[mi], bv[ni], acc[mi][ni], 0, 0, 0);                     \
        __builtin_amdgcn_s_setprio(0);                                         \
    } } while (0)

    STAGE(A0, B0, 0);
    __syncthreads();
#pragma unroll 1
    for (int pp = 0; pp < 18; pp += 2) {
        STAGE(A1, B1, pp + 1);          // issue next-phase loads (hidden under compute)
        COMPUTE(A0, B0);
        __syncthreads();                // drains pp+1's loads (mostly landed)
        if (pp < 16) STAGE(A0, B0, pp + 2);
        COMPUTE(A1, B1);
        __syncthreads();
    }
#undef STAGE
#undef COMPUTE

    // --- fused per-block BN stats
    float sv[4], qv[4];
#pragma unroll
    for (int ni = 0; ni < 4; ++ni) {
        float a = 0.f, b = 0.f;
#pragma unroll
        for (int mi = 0; mi < 4; ++mi)
#pragma unroll
            for (int q = 0; q < 4; ++q) { float v = acc[mi][ni][q]; a += v; b += v * v; }
        a += __shfl_xor(a, 16); a += __shfl_xor(a, 32);
        b += __shfl_xor(b, 16); b += __shfl_xor(b, 32);
        sv[ni] = a; qv[ni] = b;
    }
    float2* sred = (float2*)(smem + 20480);   // byte 40960, past transpose tile
    if (lane < 16) {
#pragma unroll
        for (int ni = 0; ni < 4; ++ni)
            sred[wid * 64 + ni * 16 + lane] = make_float2(sv[ni], qv[ni]);
    }

    // --- transpose acc -> [128 px][136 pad] bf16, coalesced store
#pragma unroll
    for (int mi = 0; mi < 4; ++mi)
#pragma unroll
        for (int ni = 0; ni < 4; ++ni)
#pragma unroll
            for (int q = 0; q < 4; ++q)
                smem[(m0 + mi * 16 + lhk * 4 + q) * 136 + n0 + ni * 16 + lrow] =
                    f2bf(acc[mi][ni][q]);
    __syncthreads();
    {
        const int px = t >> 1, half = t & 1;
        const u16* src = &smem[px * 136 + half * 64];
        u16* dst = y + (size_t)(pm0 + px) * 128 + half * 64;
#pragma unroll
        for (int j = 0; j < 8; ++j)
            *(u16x8*)(dst + j * 8) = *(const u16x8*)(src + j * 8);
    }
    if (t < 128) {
        const int ni = (t >> 4) & 3, oc = t & 15, hi = t >> 6;
        float2 u = sred[hi * 64 + ni * 16 + oc];
        float2 v = sred[(hi + 2) * 64 + ni * 16 + oc];
        partial[(size_t)t * 784 + bid] = make_float2(u.x + v.x, u.y + v.y);
    }
}

// ---- reduce partials -> BN coef (a,b): y' = a*y + b ----
__global__ void stats_finalize(const float2* __restrict__ partial,
                               const float* __restrict__ gamma, const float* __restrict__ beta,
                               float2* __restrict__ coef) {
    __shared__ float ss[256], ss2[256];
    const int c = blockIdx.x, t = threadIdx.x;
    const float2* pc = partial + (size_t)c * 784;
    float s = 0.f, s2 = 0.f;
    for (int i = t; i < 784; i += 256) { float2 v = pc[i]; s += v.x; s2 += v.y; }
    ss[t] = s; ss2[t] = s2;
    __syncthreads();
    for (int o = 128; o > 0; o >>= 1) {
        if (t < o) { ss[t] += ss[t + o]; ss2[t] += ss2[t + o]; }
        __syncthreads();
    }
    if (t == 0) {
        double mean = (double)ss[0] / (double)NPIX;
        double var  = (double)ss2[0] / (double)NPIX - mean * mean;
        if (var < 0.0) var = 0.0;
        float inv = rsqrtf((float)var + 1e-5f);
        float a = gamma[c] * inv;
        coef[c] = make_float2(a, beta[c] - (float)mean * a);
    }
}

// ---- BN1 + ReLU: y (linear NHWC) -> padded NHWC bf16 (interior) ----
__global__ void bnrelu_kernel(const u16* __restrict__ y, const float2* __restrict__ coef,
                              u16* __restrict__ xbp) {
    __shared__ float2 sc[128];
    const int t = threadIdx.x;
    if (t < 128) sc[t] = coef[t];
    __syncthreads();
    size_t i = (size_t)blockIdx.x * 256 + t;
    u16x8 v = *(const u16x8*)(y + i * 8);
    int p  = (int)(i >> 4);
    int c0 = (int)(i & 15) * 8;
    int n   = p / HW;
    int rem = p - n * HW;
    int h   = rem / 56;
    int w   = rem - h * 56;
    u16x8 o;
#pragma unroll
    for (int j = 0; j < 8; ++j) {
        float2 k = sc[c0 + j];
        o[j] = f2bf(fmaxf(bf2f(v[j]) * k.x + k.y, 0.f));
    }
    *(u16x8*)(xbp + ((size_t)(n * PADR + (h + 1) * 58 + (w + 1))) * 128 + c0) = o;
}

// ---- BN2 + residual + ReLU + NHWC->NCHW f32 ----
__global__ void bn_add_relu_nchw(const u16* __restrict__ y2, const float2* __restrict__ coef,
                                 const float* __restrict__ x, float* __restrict__ out) {
    __shared__ float tile[32][65];
    __shared__ float2 sc[32];
    const int t = threadIdx.x;
    const int n = blockIdx.y;
    const int ct = blockIdx.x & 3;
    const int pt = blockIdx.x >> 2;
    const int c0 = ct * 32, p0 = pt * 64;
    if (t < 32) sc[t] = coef[c0 + t];
    __syncthreads();
    {
        const int p  = t >> 2;
        const int cs = (t & 3) * 8;
        const u16x8 v = *(const u16x8*)(y2 + ((size_t)(n * HW + p0 + p)) * 128 + c0 + cs);
#pragma unroll
        for (int j = 0; j < 8; ++j) {
            float2 k = sc[cs + j];
            tile[cs + j][p] = bf2f(v[j]) * k.x + k.y;
        }
    }
    __syncthreads();
    {
        const int c  = t >> 3;
        const int pw = (t & 7) * 8;
        const size_t ob = ((size_t)(n * 128 + c0 + c)) * HW + p0 + pw;
        const float4 x0 = *(const float4*)(x + ob);
        const float4 x1 = *(const float4*)(x + ob + 4);
        float4 o0, o1;
        o0.x = fmaxf(tile[c][pw + 0] + x0.x, 0.f);
        o0.y = fmaxf(tile[c][pw + 1] + x0.y, 0.f);
        o0.z = fmaxf(tile[c][pw + 2] + x0.z, 0.f);
        o0.w = fmaxf(tile[c][pw + 3] + x0.w, 0.f);
        o1.x = fmaxf(tile[c][pw + 4] + x1.x, 0.f);
        o1.y = fmaxf(tile[c][pw + 5] + x1.y, 0.f);
        o1.z = fmaxf(tile[c][pw + 6] + x1.z, 0.f);
        o1.w = fmaxf(tile[c][pw + 7] + x1.w, 0.f);
        *(float4*)(out + ob) = o0;
        *(float4*)(out + ob + 4) = o1;
    }
}

extern "C" void kernel_launch(void* const* d_in, const int* in_sizes, int n_in,
                              void* d_out, int out_size, void* d_ws, size_t ws_size,
                              hipStream_t stream) {
    const float* x  = (const float*)d_in[0];
    const float* w1 = (const float*)d_in[1];
    const float* g1 = (const float*)d_in[2];
    const float* b1 = (const float*)d_in[3];
    const float* w2 = (const float*)d_in[4];
    const float* g2 = (const float*)d_in[5];
    const float* b2 = (const float*)d_in[6];
    float* out = (float*)d_out;
    char* ws = (char*)d_ws;

    u16*    xbp  = (u16*)(ws);                         // padded NHWC, 27557888 B (reused as out1)
    u16*    ybuf = (u16*)(ws + 27557888);              // conv out NHWC, 25690112 B
    u16*    Bm1  = (u16*)(ws + 53248000);
    u16*    Bm2  = (u16*)(ws + 53542912);
    float2* part = (float2*)(ws + 53837824);
    float2* cf1  = (float2*)(ws + 54640640);
    float2* cf2  = (float2*)(ws + 54641664);

    setup_kernel<<<1608, 256, 0, stream>>>(w1, w2, Bm1, Bm2, xbp);
    x_to_nhwc<<<dim3(196, 32), 256, 0, stream>>>(x, xbp);

    conv_mfma<<<784, 256, 0, stream>>>(xbp, Bm1, ybuf, part);
    stats_finalize<<<128, 256, 0, stream>>>(part, g1, b1, cf1);
    bnrelu_kernel<<<6272, 256, 0, stream>>>(ybuf, cf1, xbp);

    conv_mfma<<<784, 256, 0, stream>>>(xbp, Bm2, ybuf, part);
    stats_finalize<<<128, 256, 0, stream>>>(part, g2, b2, cf2);
    bn_add_relu_nchw<<<dim3(196, 32), 256, 0, stream>>>(ybuf, cf2, x, out);
}